// Round 10
// baseline (1430.895 us; speedup 1.0000x reference)
//
#include <hip/hip_runtime.h>

#define H_DIM 4096
#define I_DIM 14336
#define T_DIM 4096
#define N2    (2*I_DIM)   // 28672 — gate/up interleaved in 16-col groups

typedef float  f32x4  __attribute__((ext_vector_type(4)));
typedef float  f32x2  __attribute__((ext_vector_type(2)));
typedef unsigned int u32x4 __attribute__((ext_vector_type(4)));
typedef unsigned int u32x2 __attribute__((ext_vector_type(2)));
typedef __bf16 bf16x8 __attribute__((ext_vector_type(8)));
typedef unsigned short u16;

// fp32 -> bf16 (RNE)
__device__ __forceinline__ unsigned int pack2bf(float a, float b){
  unsigned int ua = __builtin_bit_cast(unsigned int, a);
  unsigned int ub = __builtin_bit_cast(unsigned int, b);
  ua = (ua + 0x7fffu + ((ua >> 16) & 1u)) >> 16;
  ub = (ub + 0x7fffu + ((ub >> 16) & 1u)) >> 16;
  return (ua & 0xffffu) | (ub << 16);
}
__device__ __forceinline__ u16 f2bf(float a){
  unsigned int u = __builtin_bit_cast(unsigned int, a);
  u = (u + 0x7fffu + ((u >> 16) & 1u)) >> 16;
  return (u16)u;
}
__device__ __forceinline__ bf16x8 lds_frag(const unsigned char* p){
  u32x4 v = *(const u32x4*)p;
  return __builtin_bit_cast(bf16x8, v);
}

#define GLOAD16(g, l) __builtin_amdgcn_global_load_lds( \
    (const __attribute__((address_space(1))) unsigned int*)(g), \
    (__attribute__((address_space(3))) unsigned int*)(l), 16, 0, 0)

#define WAITVM4  asm volatile("s_waitcnt vmcnt(4)" ::: "memory")
#define WAITVM0  asm volatile("s_waitcnt vmcnt(0)" ::: "memory")
#define CFENCE   asm volatile("" ::: "memory")

// ---------------------------------------------------------------------------
// fp32 -> bf16 cast (same layout), 8 elems/thread
// ---------------------------------------------------------------------------
__global__ __launch_bounds__(256)
void k_cast(const float* __restrict__ in, u16* __restrict__ out, long n)
{
  long i = ((long)blockIdx.x * 256 + threadIdx.x) * 8;
  if (i >= n) return;
  f32x4 a = *(const f32x4*)(in + i);
  f32x4 b = *(const f32x4*)(in + i + 4);
  u32x4 o = { pack2bf(a[0],a[1]), pack2bf(a[2],a[3]),
              pack2bf(b[0],b[1]), pack2bf(b[2],b[3]) };
  *(u32x4*)(out + i) = o;
}

// ---------------------------------------------------------------------------
// fp32 [R][C] -> bf16 transposed [C][R], optional gate/up 16-col interleave.
// ---------------------------------------------------------------------------
__global__ __launch_bounds__(256)
void k_transpose(const float* __restrict__ in, u16* __restrict__ out,
                 int R, int C, int remap)
{
  __shared__ u16 tile[64][68];
  const int tid = threadIdx.x;
  const int r0 = blockIdx.x * 64, c0 = blockIdx.y * 64;
  const int lr  = tid >> 4;
  const int lc4 = (tid & 15) * 4;
  #pragma unroll
  for (int s = 0; s < 4; ++s){
    f32x4 v = *(const f32x4*)(in + (size_t)(r0 + lr + s*16) * C + c0 + lc4);
    #pragma unroll
    for (int j = 0; j < 4; ++j) tile[lc4 + j][lr + s*16] = f2bf(v[j]);
  }
  __syncthreads();
  #pragma unroll
  for (int s = 0; s < 4; ++s){
    int cl = lr + s*16;
    int n  = c0 + cl;
    int orow = (remap < 0) ? n : (((n >> 4) << 5) + (n & 15) + remap);
    u32x2 v = *(const u32x2*)&tile[cl][lc4];
    *(u32x2*)(out + (size_t)orow * R + r0 + lc4) = v;
  }
}

// ---------------------------------------------------------------------------
// 256x256 bf16 GEMM, C = A(MxK) * B^T(NxK).  BK=64, 512 thr (8 waves 2Mx4N),
// 128 KiB LDS = 8 x 16 KiB half-tile slots {B0,B1,A0,A1} x 2-tile parity.
// XOR granule swizzle (g ^= row&7): pre-swizzled global src + swizzled
// ds_read, linear global_load_lds dest.
// Round-10 schedule: 4 phases per K-tile, ONE barrier per phase.
// Phase = {ds-reads for this quadrant; 1 half-tile ISSUE; setprio(1);
// 16 MFMA; setprio(0); barrier}.  No lgkm asm (compiler emits counted
// lgkmcnt from SSA deps); vmcnt(4) once per K-tile at P3 (2 half-tiles
// stay in flight across the boundary; tail drains vmcnt(0)).
// Ledger (audited r10): at each tile boundary everything <= bh+7 is
// verified (tile t+1 complete); each ISSUE's target slot is separated
// from its readers by >= 1 barrier:
//   P0: ISSUE bh+6 -> slot A0(t-1), read in t-1 P0/P2, barriers since.
//   P1: ISSUE bh+7 -> slot A1(t-1), same.
//   P2: ISSUE bh+8 -> slot B0(t), read in P0/P1, P1-end barrier between.
//   P3: ISSUE bh+9 -> slot B1(t), read in P0/P1, P2-end barrier between.
// EPI=0: f32 out.  EPI=1: (gate,up) 16-col pairs -> silu(g)*u bf16, ldc cols.
// ---------------------------------------------------------------------------
template<int EPI>
__global__ __launch_bounds__(512, 2)
void gemm10(const u16* __restrict__ A, const u16* __restrict__ B,
            void* __restrict__ Cout, const int K, const int ldc,
            const int mblocks)
{
  __shared__ unsigned char smem[131072];
  const int tid  = threadIdx.x;
  const int lane = tid & 63;
  const int wid  = tid >> 6;
  const int wm   = wid >> 2;       // 0..1  (128 rows each)
  const int wn   = wid & 3;        // 0..3  (64 cols each)

  // XCD-aware swizzle (gridDim.x % 8 == 0 for both our grids)
  const int nwg = gridDim.x;
  const int cpx = nwg >> 3;
  const int bid = blockIdx.x;
  const int swz = (bid & 7) * cpx + (bid >> 3);
  const int m0 = (swz % mblocks) << 8;
  const int n0 = (swz / mblocks) << 8;
  const int NT = K >> 6;

  // staging: thread t covers (row = i*64 + t>>3, phys granule t&7)
  const int srow = tid >> 3;
  const int gl   = (tid & 7) ^ (srow & 7);    // logical granule (involution)
  const u16* Ap = A + (size_t)(m0 + srow) * K + gl * 8;
  const u16* Bp = B + (size_t)(n0 + srow) * K + gl * 8;
  unsigned char* ldsw = smem + tid * 16;
  const size_t rowK64  = (size_t)64 * K;
  const size_t rowK128 = (size_t)128 * K;

  // frag-read precompute: physical granule = (kk*4+lhi) ^ (row&7)
  const int r15 = lane & 15;
  const int lhi = lane >> 4;
  const int gk0 = (((r15 >> 2) & 1) << 2) | (lhi ^ (r15 & 3));
  const int gk1 = gk0 ^ 4;
  const unsigned char* ldsr = smem + r15 * 128;

  f32x4 acc[8][4];
  #pragma unroll
  for (int i = 0; i < 8; ++i)
    #pragma unroll
    for (int j = 0; j < 4; ++j) acc[i][j] = (f32x4)0.0f;
  bf16x8 areg0[4][2], areg1[4][2];   // dual A-frag sets
  bf16x8 breg[2][2][2];              // [nq][nj2][kk]

#define ISSUE(h) do { \
    const int _a = (h) & 3; \
    const size_t _k0 = (size_t)((h) >> 2) << 6; \
    unsigned char* _l = ldsw + (((h) & 7) << 14); \
    const u16* _s = (_a < 2 ? Bp + (size_t)_a * rowK128 \
                            : Ap + (size_t)(_a - 2) * rowK128) + _k0; \
    GLOAD16(_s, _l); \
    GLOAD16(_s + rowK64, _l + 8192); \
  } while (0)

#define RD_A(SLOT, MQ, DST) do { \
    const unsigned char* _b = ldsr + ((SLOT) << 14) + (MQ) * 8192; \
    _Pragma("unroll") \
    for (int _m = 0; _m < 4; ++_m) { \
      DST[_m][0] = lds_frag(_b + _m * 2048 + gk0 * 16); \
      DST[_m][1] = lds_frag(_b + _m * 2048 + gk1 * 16); \
    } \
  } while (0)

#define RD_B(SLOT, NQ) do { \
    const unsigned char* _b = ldsr + ((SLOT) << 14) + (wn & 1) * 8192 + (NQ) * 4096; \
    _Pragma("unroll") \
    for (int _n = 0; _n < 2; ++_n) { \
      breg[NQ][_n][0] = lds_frag(_b + _n * 2048 + gk0 * 16); \
      breg[NQ][_n][1] = lds_frag(_b + _n * 2048 + gk1 * 16); \
    } \
  } while (0)

#define MFMAQ(AR, MQ, NQ) \
    _Pragma("unroll") \
    for (int _m = 0; _m < 4; ++_m) \
      _Pragma("unroll") \
      for (int _n = 0; _n < 2; ++_n) { \
        acc[(MQ)*4+_m][(NQ)*2+_n] = __builtin_amdgcn_mfma_f32_16x16x32_bf16( \
            AR[_m][0], breg[NQ][_n][0], acc[(MQ)*4+_m][(NQ)*2+_n], 0, 0, 0); \
        acc[(MQ)*4+_m][(NQ)*2+_n] = __builtin_amdgcn_mfma_f32_16x16x32_bf16( \
            AR[_m][1], breg[NQ][_n][1], acc[(MQ)*4+_m][(NQ)*2+_n], 0, 0, 0); \
      }

  // prologue: stage tile 0 fully + B-halves of tile 1 (6 half-tiles)
  #pragma unroll
  for (int h = 0; h < 6; ++h) ISSUE(h);
  WAITVM4;                      // tile 0 verified; h4,h5 stay in flight
  __builtin_amdgcn_s_barrier();
  CFENCE;

  for (int t = 0; t < NT; ++t){
    const int bh = t << 2;
    const int sB = (bh + (wn >> 1)) & 7;   // wave's B half slot
    const int sA = (bh + 2 + wm) & 7;      // wave's A half slot
    const int lim = NT << 2;
    // ---- P0: A0 (8 rd) + B0 (4 rd); ISSUE bh+6; Q(0,0)
    RD_A(sA, 0, areg0);
    RD_B(sB, 0);
    if (bh + 6 < lim) ISSUE(bh + 6);
    __builtin_amdgcn_s_setprio(1);
    MFMAQ(areg0, 0, 0);
    __builtin_amdgcn_s_setprio(0);
    __builtin_amdgcn_s_barrier();
    CFENCE;
    // ---- P1: B1 (4 rd); ISSUE bh+7; Q(0,1)
    RD_B(sB, 1);
    if (bh + 7 < lim) ISSUE(bh + 7);
    __builtin_amdgcn_s_setprio(1);
    MFMAQ(areg0, 0, 1);
    __builtin_amdgcn_s_setprio(0);
    __builtin_amdgcn_s_barrier();
    CFENCE;
    // ---- P2: A1 (8 rd); ISSUE bh+8; Q(1,1)
    RD_A(sA, 1, areg1);
    if (bh + 8 < lim) ISSUE(bh + 8);
    __builtin_amdgcn_s_setprio(1);
    MFMAQ(areg1, 1, 1);
    __builtin_amdgcn_s_setprio(0);
    __builtin_amdgcn_s_barrier();
    CFENCE;
    // ---- P3: no rd; ISSUE bh+9; Q(1,0); counted vmcnt checkpoint
    if (bh + 9 < lim) ISSUE(bh + 9);
    __builtin_amdgcn_s_setprio(1);
    MFMAQ(areg1, 1, 0);
    __builtin_amdgcn_s_setprio(0);
    if (t + 2 < NT) { WAITVM4; } else { WAITVM0; }   // tail drains fully
    __builtin_amdgcn_s_barrier();
    CFENCE;
  }

#undef ISSUE
#undef RD_A
#undef RD_B
#undef MFMAQ

  // epilogue
  const int r0 = lhi * 4;
  if (EPI == 0){
    float* C = (float*)Cout;
    #pragma unroll
    for (int mi = 0; mi < 8; ++mi)
      #pragma unroll
      for (int nj = 0; nj < 4; ++nj)
        #pragma unroll
        for (int j = 0; j < 4; ++j)
          C[(size_t)(m0 + wm*128 + mi*16 + r0 + j) * ldc + n0 + wn*64 + nj*16 + r15] =
            acc[mi][nj][j];
  } else {
    u16* C = (u16*)Cout;
    const int hb = ((n0 + wn*64) >> 1);
    #pragma unroll
    for (int mi = 0; mi < 8; ++mi)
      #pragma unroll
      for (int p = 0; p < 2; ++p)
        #pragma unroll
        for (int j = 0; j < 4; ++j){
          float g = acc[mi][2*p][j];
          float u = acc[mi][2*p+1][j];
          float s = g / (1.0f + __expf(-g));
          C[(size_t)(m0 + wm*128 + mi*16 + r0 + j) * ldc + hb + p*16 + r15] =
            f2bf(s * u);
        }
  }
}

// ===========================================================================
// Fallback path (small workspace): round-1 kernels.
// ===========================================================================
__global__ __launch_bounds__(256, 2)
void k_gateup_fb(const float* __restrict__ x, const float* __restrict__ wg,
                 const float* __restrict__ wu, u16* __restrict__ h)
{
  __shared__ unsigned char smem[61440];
  const int tid  = threadIdx.x;
  const int lane = tid & 63;
  const int wid  = tid >> 6;
  const int wr   = wid >> 1, wc = wid & 1;
  const int m0   = blockIdx.x * 128;
  const int n0   = blockIdx.y * 128;
  const int s_am = tid >> 3;
  const int s_ak = (tid & 7) * 4;
  const int s_bn = (tid & 63) * 2;
  const int s_bk = (tid >> 6) * 8;

  f32x4 accg[4][4], accu[4][4];
  #pragma unroll
  for (int i = 0; i < 4; ++i)
    #pragma unroll
    for (int j = 0; j < 4; ++j){ accg[i][j] = (f32x4)0.0f; accu[i][j] = (f32x4)0.0f; }

  f32x4 pa[4];
  f32x2 pg[8], pu[8];
  auto gload = [&](int kt){
    const int k0 = kt * 32;
    #pragma unroll
    for (int it = 0; it < 4; ++it)
      pa[it] = *(const f32x4*)(x + (size_t)(m0 + it*32 + s_am) * H_DIM + k0 + s_ak);
    #pragma unroll
    for (int r = 0; r < 8; ++r){
      pg[r] = *(const f32x2*)(wg + (size_t)(k0 + s_bk + r) * I_DIM + n0 + s_bn);
      pu[r] = *(const f32x2*)(wu + (size_t)(k0 + s_bk + r) * I_DIM + n0 + s_bn);
    }
  };
  auto sstore = [&](int b){
    unsigned char* Ab = smem + b * 10240;
    #pragma unroll
    for (int it = 0; it < 4; ++it){
      u32x2 v = { pack2bf(pa[it][0], pa[it][1]), pack2bf(pa[it][2], pa[it][3]) };
      *(u32x2*)(Ab + (s_am + it*32) * 80 + s_ak * 2) = v;
    }
    unsigned char* Bg = smem + 20480 + b * 10240;
    unsigned char* Bu = smem + 40960 + b * 10240;
    #pragma unroll
    for (int c = 0; c < 2; ++c){
      u32x4 vg = { pack2bf(pg[0][c], pg[1][c]), pack2bf(pg[2][c], pg[3][c]),
                   pack2bf(pg[4][c], pg[5][c]), pack2bf(pg[6][c], pg[7][c]) };
      *(u32x4*)(Bg + (s_bn + c) * 80 + s_bk * 2) = vg;
      u32x4 vu = { pack2bf(pu[0][c], pu[1][c]), pack2bf(pu[2][c], pu[3][c]),
                   pack2bf(pu[4][c], pu[5][c]), pack2bf(pu[6][c], pu[7][c]) };
      *(u32x4*)(Bu + (s_bn + c) * 80 + s_bk * 2) = vu;
    }
  };
  const int koff = (lane >> 4) * 16;
  const int ar   = wr * 64 + (lane & 15);
  const int br   = wc * 64 + (lane & 15);
  auto compute = [&](int b){
    const unsigned char* Ab = smem + b * 10240;
    const unsigned char* Bg = smem + 20480 + b * 10240;
    const unsigned char* Bu = smem + 40960 + b * 10240;
    bf16x8 a[4];
    #pragma unroll
    for (int mi = 0; mi < 4; ++mi)
      a[mi] = lds_frag(Ab + (ar + mi*16) * 80 + koff);
    #pragma unroll
    for (int nh = 0; nh < 2; ++nh){
      bf16x8 bg[2], bu[2];
      #pragma unroll
      for (int nj = 0; nj < 2; ++nj){
        bg[nj] = lds_frag(Bg + (br + (nh*2+nj)*16) * 80 + koff);
        bu[nj] = lds_frag(Bu + (br + (nh*2+nj)*16) * 80 + koff);
      }
      #pragma unroll
      for (int mi = 0; mi < 4; ++mi)
        #pragma unroll
        for (int nj = 0; nj < 2; ++nj){
          accg[mi][nh*2+nj] = __builtin_amdgcn_mfma_f32_16x16x32_bf16(a[mi], bg[nj], accg[mi][nh*2+nj], 0, 0, 0);
          accu[mi][nh*2+nj] = __builtin_amdgcn_mfma_f32_16x16x32_bf16(a[mi], bu[nj], accu[mi][nh*2+nj], 0, 0, 0);
        }
    }
  };
  gload(0); sstore(0); __syncthreads();
  const int NT = H_DIM / 32;
  for (int kt = 0; kt < NT; ++kt){
    const int b = kt & 1;
    if (kt + 1 < NT) gload(kt + 1);
    compute(b);
    if (kt + 1 < NT) sstore(b ^ 1);
    __syncthreads();
  }
  const int bm = wr * 64 + ((lane >> 4) << 2);
  const int bn = wc * 64 + (lane & 15);
  #pragma unroll
  for (int mi = 0; mi < 4; ++mi)
    #pragma unroll
    for (int ni = 0; ni < 4; ++ni)
      #pragma unroll
      for (int r = 0; r < 4; ++r){
        float gv = accg[mi][ni][r];
        float uv = accu[mi][ni][r];
        float s  = gv / (1.0f + __expf(-gv));
        h[(size_t)(m0 + bm + mi*16 + r) * I_DIM + n0 + bn + ni*16] = f2bf(s * uv);
      }
}

__global__ __launch_bounds__(256, 2)
void k_down_fb(const u16* __restrict__ h, const float* __restrict__ wd,
               float* __restrict__ out)
{
  __shared__ unsigned char smem[40960];
  const int tid  = threadIdx.x;
  const int lane = tid & 63;
  const int wid  = tid >> 6;
  const int wr   = wid >> 1, wc = wid & 1;
  const int m0   = blockIdx.x * 128;
  const int n0   = blockIdx.y * 128;
  const int s_am = tid >> 1;
  const int s_ak = (tid & 1) * 16;
  const int s_bn = (tid & 63) * 2;
  const int s_bk = (tid >> 6) * 8;

  f32x4 acc[4][4];
  #pragma unroll
  for (int i = 0; i < 4; ++i)
    #pragma unroll
    for (int j = 0; j < 4; ++j) acc[i][j] = (f32x4)0.0f;

  u32x4 pha[2];
  f32x2 pb[8];
  auto gload = [&](int kt){
    const int k0 = kt * 32;
    const u16* ap = h + (size_t)(m0 + s_am) * I_DIM + k0 + s_ak;
    pha[0] = *(const u32x4*)(ap);
    pha[1] = *(const u32x4*)(ap + 8);
    #pragma unroll
    for (int r = 0; r < 8; ++r)
      pb[r] = *(const f32x2*)(wd + (size_t)(k0 + s_bk + r) * H_DIM + n0 + s_bn);
  };
  auto sstore = [&](int b){
    unsigned char* Ab = smem + b * 10240;
    *(u32x4*)(Ab + s_am * 80 + s_ak * 2)      = pha[0];
    *(u32x4*)(Ab + s_am * 80 + s_ak * 2 + 16) = pha[1];
    unsigned char* Bb = smem + 20480 + b * 10240;
    #pragma unroll
    for (int c = 0; c < 2; ++c){
      u32x4 v = { pack2bf(pb[0][c], pb[1][c]), pack2bf(pb[2][c], pb[3][c]),
                  pack2bf(pb[4][c], pb[5][c]), pack2bf(pb[6][c], pb[7][c]) };
      *(u32x4*)(Bb + (s_bn + c) * 80 + s_bk * 2) = v;
    }
  };
  const int koff = (lane >> 4) * 16;
  const int ar   = wr * 64 + (lane & 15);
  const int br   = wc * 64 + (lane & 15);
  auto compute = [&](int b){
    const unsigned char* Ab = smem + b * 10240;
    const unsigned char* Bb = smem + 20480 + b * 10240;
    bf16x8 a[4];
    #pragma unroll
    for (int mi = 0; mi < 4; ++mi)
      a[mi] = lds_frag(Ab + (ar + mi*16) * 80 + koff);
    #pragma unroll
    for (int nh = 0; nh < 2; ++nh){
      bf16x8 bb[2];
      #pragma unroll
      for (int nj = 0; nj < 2; ++nj)
        bb[nj] = lds_frag(Bb + (br + (nh*2+nj)*16) * 80 + koff);
      #pragma unroll
      for (int mi = 0; mi < 4; ++mi)
        #pragma unroll
        for (int nj = 0; nj < 2; ++nj)
          acc[mi][nh*2+nj] = __builtin_amdgcn_mfma_f32_16x16x32_bf16(a[mi], bb[nj], acc[mi][nh*2+nj], 0, 0, 0);
    }
  };
  gload(0); sstore(0); __syncthreads();
  const int NT = I_DIM / 32;
  for (int kt = 0; kt < NT; ++kt){
    const int b = kt & 1;
    if (kt + 1 < NT) gload(kt + 1);
    compute(b);
    if (kt + 1 < NT) sstore(b ^ 1);
    __syncthreads();
  }
  const int bm = wr * 64 + ((lane >> 4) << 2);
  const int bn = wc * 64 + (lane & 15);
  #pragma unroll
  for (int mi = 0; mi < 4; ++mi)
    #pragma unroll
    for (int ni = 0; ni < 4; ++ni)
      #pragma unroll
      for (int r = 0; r < 4; ++r)
        out[(size_t)(m0 + bm + mi*16 + r) * H_DIM + n0 + bn + ni*16] = acc[mi][ni][r];
}

// ---------------------------------------------------------------------------
extern "C" void kernel_launch(void* const* d_in, const int* in_sizes, int n_in,
                              void* d_out, int out_size, void* d_ws, size_t ws_size,
                              hipStream_t stream)
{
  const float* x  = (const float*)d_in[0];
  const float* wg = (const float*)d_in[1];
  const float* wu = (const float*)d_in[2];
  const float* wd = (const float*)d_in[3];
  float* out = (float*)d_out;

  const size_t X_OFF   = 0;            // x bf16:   33,554,432
  const size_t WGU_OFF = 33554432;     // wguT:    234,881,024
  const size_t WD_OFF  = 268435456;    // wdT:     117,440,512
  const size_t H_OFF   = 385875968;    // h:       117,440,512
  const size_t NEED    = 503316480;

  if (ws_size >= NEED){
    u16* xb  = (u16*)((char*)d_ws + X_OFF);
    u16* wgu = (u16*)((char*)d_ws + WGU_OFF);   // [28672][4096]
    u16* wdt = (u16*)((char*)d_ws + WD_OFF);    // [4096][14336]
    u16* h   = (u16*)((char*)d_ws + H_OFF);     // [4096][14336]

    long nx = (long)T_DIM * H_DIM;
    k_cast<<<(unsigned)((nx/8 + 255)/256), 256, 0, stream>>>(x, xb, nx);
    dim3 tg(H_DIM/64, I_DIM/64);
    k_transpose<<<tg, 256, 0, stream>>>(wg, wgu, H_DIM, I_DIM, 0);
    k_transpose<<<tg, 256, 0, stream>>>(wu, wgu, H_DIM, I_DIM, 16);
    dim3 td(I_DIM/64, H_DIM/64);
    k_transpose<<<td, 256, 0, stream>>>(wd, wdt, I_DIM, H_DIM, -1);

    // fused gate+up: M=4096, N=28672, K=4096 -> 16 x 112 = 1792 blocks
    gemm10<1><<<dim3(16 * (N2/256)), dim3(512), 0, stream>>>(
        xb, wgu, h, H_DIM, I_DIM, T_DIM/256);
    // down: M=4096, N=4096, K=14336 -> 16 x 16 = 256 blocks
    gemm10<0><<<dim3(16 * (H_DIM/256)), dim3(512), 0, stream>>>(
        h, wdt, out, I_DIM, H_DIM, T_DIM/256);
  } else {
    u16* h = (u16*)d_ws;
    size_t maxrows = ws_size / ((size_t)I_DIM * 2);
    int chunk = (int)(maxrows > (size_t)T_DIM ? (size_t)T_DIM : maxrows);
    chunk &= ~127;
    if (chunk < 128) chunk = 128;
    for (int r0 = 0; r0 < T_DIM; r0 += chunk){
      int rows = (T_DIM - r0 < chunk) ? (T_DIM - r0) : chunk;
      dim3 g1(rows / 128, I_DIM / 128);
      dim3 g2(rows / 128, H_DIM / 128);
      k_gateup_fb<<<g1, dim3(256), 0, stream>>>(x + (size_t)r0 * H_DIM, wg, wu, h);
      k_down_fb  <<<g2, dim3(256), 0, stream>>>(h, wd, out + (size_t)r0 * H_DIM);
    }
  }
}

// Round 11
// 1417.371 us; speedup vs baseline: 1.0095x; 1.0095x over previous
//
#include <hip/hip_runtime.h>

#define H_DIM 4096
#define I_DIM 14336
#define T_DIM 4096
#define N2    (2*I_DIM)   // 28672 — gate/up interleaved in 16-col groups

typedef float  f32x4  __attribute__((ext_vector_type(4)));
typedef float  f32x2  __attribute__((ext_vector_type(2)));
typedef unsigned int u32x4 __attribute__((ext_vector_type(4)));
typedef unsigned int u32x2 __attribute__((ext_vector_type(2)));
typedef __bf16 bf16x8 __attribute__((ext_vector_type(8)));
typedef unsigned short u16;

// fp32 -> bf16 (RNE)
__device__ __forceinline__ unsigned int pack2bf(float a, float b){
  unsigned int ua = __builtin_bit_cast(unsigned int, a);
  unsigned int ub = __builtin_bit_cast(unsigned int, b);
  ua = (ua + 0x7fffu + ((ua >> 16) & 1u)) >> 16;
  ub = (ub + 0x7fffu + ((ub >> 16) & 1u)) >> 16;
  return (ua & 0xffffu) | (ub << 16);
}
__device__ __forceinline__ u16 f2bf(float a){
  unsigned int u = __builtin_bit_cast(unsigned int, a);
  u = (u + 0x7fffu + ((u >> 16) & 1u)) >> 16;
  return (u16)u;
}
__device__ __forceinline__ bf16x8 lds_frag(const unsigned char* p){
  u32x4 v = *(const u32x4*)p;
  return __builtin_bit_cast(bf16x8, v);
}

#define GLOAD16(g, l) __builtin_amdgcn_global_load_lds( \
    (const __attribute__((address_space(1))) unsigned int*)(g), \
    (__attribute__((address_space(3))) unsigned int*)(l), 16, 0, 0)

#define WAITVM0  asm volatile("s_waitcnt vmcnt(0)" ::: "memory")
#define CFENCE   asm volatile("" ::: "memory")

// ---------------------------------------------------------------------------
// fp32 -> bf16 cast (same layout), 8 elems/thread
// ---------------------------------------------------------------------------
__global__ __launch_bounds__(256)
void k_cast(const float* __restrict__ in, u16* __restrict__ out, long n)
{
  long i = ((long)blockIdx.x * 256 + threadIdx.x) * 8;
  if (i >= n) return;
  f32x4 a = *(const f32x4*)(in + i);
  f32x4 b = *(const f32x4*)(in + i + 4);
  u32x4 o = { pack2bf(a[0],a[1]), pack2bf(a[2],a[3]),
              pack2bf(b[0],b[1]), pack2bf(b[2],b[3]) };
  *(u32x4*)(out + i) = o;
}

// ---------------------------------------------------------------------------
// fp32 [R][C] -> bf16 transposed [C][R], optional gate/up 16-col interleave.
// ---------------------------------------------------------------------------
__global__ __launch_bounds__(256)
void k_transpose(const float* __restrict__ in, u16* __restrict__ out,
                 int R, int C, int remap)
{
  __shared__ u16 tile[64][68];
  const int tid = threadIdx.x;
  const int r0 = blockIdx.x * 64, c0 = blockIdx.y * 64;
  const int lr  = tid >> 4;
  const int lc4 = (tid & 15) * 4;
  #pragma unroll
  for (int s = 0; s < 4; ++s){
    f32x4 v = *(const f32x4*)(in + (size_t)(r0 + lr + s*16) * C + c0 + lc4);
    #pragma unroll
    for (int j = 0; j < 4; ++j) tile[lc4 + j][lr + s*16] = f2bf(v[j]);
  }
  __syncthreads();
  #pragma unroll
  for (int s = 0; s < 4; ++s){
    int cl = lr + s*16;
    int n  = c0 + cl;
    int orow = (remap < 0) ? n : (((n >> 4) << 5) + (n & 15) + remap);
    u32x2 v = *(const u32x2*)&tile[cl][lc4];
    *(u32x2*)(out + (size_t)orow * R + r0 + lc4) = v;
  }
}

// ---------------------------------------------------------------------------
// 256x256 bf16 GEMM, C = A(MxK) * B^T(NxK).  BK=64, 512 thr (8 waves 2Mx4N),
// 128 KiB LDS = 8 x 16 KiB half-tile slots {B0,B1,A0,A1} x 2-tile parity.
// XOR granule swizzle (g ^= row&7): pre-swizzled global src + swizzled
// ds_read, linear global_load_lds dest.  Depth-1 prefetch, ONE vmcnt(0) +
// ONE barrier per K-tile (r9 schedule, best known).
// Round-11 change: k-OUTER MFMA ordering — 8 independent accumulators
// between every dependent acc reuse (r9's k-inner emitted 32 dependent
// back-to-back MFMA pairs per tile per wave).  B0 reads issued before A0
// so the first MFMA's lgkm position drops 9 -> 5.
// EPI=0: f32 out.  EPI=1: (gate,up) 16-col pairs -> silu(g)*u bf16, ldc cols.
// ---------------------------------------------------------------------------
template<int EPI>
__global__ __launch_bounds__(512, 2)
void gemm11(const u16* __restrict__ A, const u16* __restrict__ B,
            void* __restrict__ Cout, const int K, const int ldc,
            const int mblocks)
{
  __shared__ unsigned char smem[131072];
  const int tid  = threadIdx.x;
  const int lane = tid & 63;
  const int wid  = tid >> 6;
  const int wm   = wid >> 2;       // 0..1  (128 rows each)
  const int wn   = wid & 3;        // 0..3  (64 cols each)

  // XCD-aware swizzle (gridDim.x % 8 == 0 for both our grids)
  const int nwg = gridDim.x;
  const int cpx = nwg >> 3;
  const int bid = blockIdx.x;
  const int swz = (bid & 7) * cpx + (bid >> 3);
  const int m0 = (swz % mblocks) << 8;
  const int n0 = (swz / mblocks) << 8;
  const int NT = K >> 6;

  // staging: thread t covers (row = i*64 + t>>3, phys granule t&7)
  const int srow = tid >> 3;
  const int gl   = (tid & 7) ^ (srow & 7);    // logical granule (involution)
  const u16* Ap = A + (size_t)(m0 + srow) * K + gl * 8;
  const u16* Bp = B + (size_t)(n0 + srow) * K + gl * 8;
  unsigned char* ldsw = smem + tid * 16;
  const size_t rowK64  = (size_t)64 * K;
  const size_t rowK128 = (size_t)128 * K;

  // frag-read precompute: physical granule = (kk*4+lhi) ^ (row&7)
  const int r15 = lane & 15;
  const int lhi = lane >> 4;
  const int gk0 = (((r15 >> 2) & 1) << 2) | (lhi ^ (r15 & 3));
  const int gk1 = gk0 ^ 4;
  const unsigned char* ldsr = smem + r15 * 128;

  f32x4 acc[8][4];
  #pragma unroll
  for (int i = 0; i < 8; ++i)
    #pragma unroll
    for (int j = 0; j < 4; ++j) acc[i][j] = (f32x4)0.0f;
  bf16x8 areg0[4][2], areg1[4][2];   // dual A-frag sets (pipeline)
  bf16x8 breg[2][2][2];              // [nq][nj2][kk]

#define ISSUE(h) do { \
    const int _a = (h) & 3; \
    const size_t _k0 = (size_t)((h) >> 2) << 6; \
    unsigned char* _l = ldsw + (((h) & 7) << 14); \
    const u16* _s = (_a < 2 ? Bp + (size_t)_a * rowK128 \
                            : Ap + (size_t)(_a - 2) * rowK128) + _k0; \
    GLOAD16(_s, _l); \
    GLOAD16(_s + rowK64, _l + 8192); \
  } while (0)

#define RD_A(SLOT, MQ, DST) do { \
    const unsigned char* _b = ldsr + ((SLOT) << 14) + (MQ) * 8192; \
    _Pragma("unroll") \
    for (int _m = 0; _m < 4; ++_m) { \
      DST[_m][0] = lds_frag(_b + _m * 2048 + gk0 * 16); \
      DST[_m][1] = lds_frag(_b + _m * 2048 + gk1 * 16); \
    } \
  } while (0)

#define RD_B(SLOT, NQ) do { \
    const unsigned char* _b = ldsr + ((SLOT) << 14) + (wn & 1) * 8192 + (NQ) * 4096; \
    _Pragma("unroll") \
    for (int _n = 0; _n < 2; ++_n) { \
      breg[NQ][_n][0] = lds_frag(_b + _n * 2048 + gk0 * 16); \
      breg[NQ][_n][1] = lds_frag(_b + _n * 2048 + gk1 * 16); \
    } \
  } while (0)

// k-OUTER: 8 independent acc entries between dependent reuses of the same acc
#define MFMAQ(AR, MQ, NQ) \
    _Pragma("unroll") \
    for (int _k = 0; _k < 2; ++_k) \
      _Pragma("unroll") \
      for (int _m = 0; _m < 4; ++_m) \
        _Pragma("unroll") \
        for (int _n = 0; _n < 2; ++_n) \
          acc[(MQ)*4+_m][(NQ)*2+_n] = __builtin_amdgcn_mfma_f32_16x16x32_bf16( \
              AR[_m][_k], breg[NQ][_n][_k], acc[(MQ)*4+_m][(NQ)*2+_n], 0, 0, 0);

  // prologue: stage tile 0 (4 half-tiles), wait, sync
  #pragma unroll
  for (int h = 0; h < 4; ++h) ISSUE(h);
  WAITVM0;
  __builtin_amdgcn_s_barrier();
  CFENCE;

  for (int t = 0; t < NT; ++t){
    const int bh = t << 2;
    const int sB = (bh + (wn >> 1)) & 7;   // wave's B half slot
    const int sA = (bh + 2 + wm) & 7;      // wave's A half slot
    const bool more = (t + 1 < NT);
    // stage ALL of tile t+1 (parity slots, disjoint from tile-t reads)
    if (more){ ISSUE(bh + 4); ISSUE(bh + 5); ISSUE(bh + 6); ISSUE(bh + 7); }
    // pipelined reads + MFMA; compiler emits counted lgkmcnt
    RD_B(sB, 0);                 // B0 first: first MFMA's lgkm position = 5
    RD_A(sA, 0, areg0);
    RD_B(sB, 1);
    MFMAQ(areg0, 0, 0);
    RD_A(sA, 1, areg1);          // overlaps with Q(0,0)/Q(0,1) MFMAs
    MFMAQ(areg0, 0, 1);
    MFMAQ(areg1, 1, 1);
    MFMAQ(areg1, 1, 0);
    // boundary: confirm t+1 landed, then one barrier
    if (more) WAITVM0;
    __builtin_amdgcn_s_barrier();
    CFENCE;
  }

#undef ISSUE
#undef RD_A
#undef RD_B
#undef MFMAQ

  // epilogue
  const int r0 = lhi * 4;
  if (EPI == 0){
    float* C = (float*)Cout;
    #pragma unroll
    for (int mi = 0; mi < 8; ++mi)
      #pragma unroll
      for (int nj = 0; nj < 4; ++nj)
        #pragma unroll
        for (int j = 0; j < 4; ++j)
          C[(size_t)(m0 + wm*128 + mi*16 + r0 + j) * ldc + n0 + wn*64 + nj*16 + r15] =
            acc[mi][nj][j];
  } else {
    u16* C = (u16*)Cout;
    const int hb = ((n0 + wn*64) >> 1);
    #pragma unroll
    for (int mi = 0; mi < 8; ++mi)
      #pragma unroll
      for (int p = 0; p < 2; ++p)
        #pragma unroll
        for (int j = 0; j < 4; ++j){
          float g = acc[mi][2*p][j];
          float u = acc[mi][2*p+1][j];
          float s = g / (1.0f + __expf(-g));
          C[(size_t)(m0 + wm*128 + mi*16 + r0 + j) * ldc + hb + p*16 + r15] =
            f2bf(s * u);
        }
  }
}

// ===========================================================================
// Fallback path (small workspace): round-1 kernels.
// ===========================================================================
__global__ __launch_bounds__(256, 2)
void k_gateup_fb(const float* __restrict__ x, const float* __restrict__ wg,
                 const float* __restrict__ wu, u16* __restrict__ h)
{
  __shared__ unsigned char smem[61440];
  const int tid  = threadIdx.x;
  const int lane = tid & 63;
  const int wid  = tid >> 6;
  const int wr   = wid >> 1, wc = wid & 1;
  const int m0   = blockIdx.x * 128;
  const int n0   = blockIdx.y * 128;
  const int s_am = tid >> 3;
  const int s_ak = (tid & 7) * 4;
  const int s_bn = (tid & 63) * 2;
  const int s_bk = (tid >> 6) * 8;

  f32x4 accg[4][4], accu[4][4];
  #pragma unroll
  for (int i = 0; i < 4; ++i)
    #pragma unroll
    for (int j = 0; j < 4; ++j){ accg[i][j] = (f32x4)0.0f; accu[i][j] = (f32x4)0.0f; }

  f32x4 pa[4];
  f32x2 pg[8], pu[8];
  auto gload = [&](int kt){
    const int k0 = kt * 32;
    #pragma unroll
    for (int it = 0; it < 4; ++it)
      pa[it] = *(const f32x4*)(x + (size_t)(m0 + it*32 + s_am) * H_DIM + k0 + s_ak);
    #pragma unroll
    for (int r = 0; r < 8; ++r){
      pg[r] = *(const f32x2*)(wg + (size_t)(k0 + s_bk + r) * I_DIM + n0 + s_bn);
      pu[r] = *(const f32x2*)(wu + (size_t)(k0 + s_bk + r) * I_DIM + n0 + s_bn);
    }
  };
  auto sstore = [&](int b){
    unsigned char* Ab = smem + b * 10240;
    #pragma unroll
    for (int it = 0; it < 4; ++it){
      u32x2 v = { pack2bf(pa[it][0], pa[it][1]), pack2bf(pa[it][2], pa[it][3]) };
      *(u32x2*)(Ab + (s_am + it*32) * 80 + s_ak * 2) = v;
    }
    unsigned char* Bg = smem + 20480 + b * 10240;
    unsigned char* Bu = smem + 40960 + b * 10240;
    #pragma unroll
    for (int c = 0; c < 2; ++c){
      u32x4 vg = { pack2bf(pg[0][c], pg[1][c]), pack2bf(pg[2][c], pg[3][c]),
                   pack2bf(pg[4][c], pg[5][c]), pack2bf(pg[6][c], pg[7][c]) };
      *(u32x4*)(Bg + (s_bn + c) * 80 + s_bk * 2) = vg;
      u32x4 vu = { pack2bf(pu[0][c], pu[1][c]), pack2bf(pu[2][c], pu[3][c]),
                   pack2bf(pu[4][c], pu[5][c]), pack2bf(pu[6][c], pu[7][c]) };
      *(u32x4*)(Bu + (s_bn + c) * 80 + s_bk * 2) = vu;
    }
  };
  const int koff = (lane >> 4) * 16;
  const int ar   = wr * 64 + (lane & 15);
  const int br   = wc * 64 + (lane & 15);
  auto compute = [&](int b){
    const unsigned char* Ab = smem + b * 10240;
    const unsigned char* Bg = smem + 20480 + b * 10240;
    const unsigned char* Bu = smem + 40960 + b * 10240;
    bf16x8 a[4];
    #pragma unroll
    for (int mi = 0; mi < 4; ++mi)
      a[mi] = lds_frag(Ab + (ar + mi*16) * 80 + koff);
    #pragma unroll
    for (int nh = 0; nh < 2; ++nh){
      bf16x8 bg[2], bu[2];
      #pragma unroll
      for (int nj = 0; nj < 2; ++nj){
        bg[nj] = lds_frag(Bg + (br + (nh*2+nj)*16) * 80 + koff);
        bu[nj] = lds_frag(Bu + (br + (nh*2+nj)*16) * 80 + koff);
      }
      #pragma unroll
      for (int mi = 0; mi < 4; ++mi)
        #pragma unroll
        for (int nj = 0; nj < 2; ++nj){
          accg[mi][nh*2+nj] = __builtin_amdgcn_mfma_f32_16x16x32_bf16(a[mi], bg[nj], accg[mi][nh*2+nj], 0, 0, 0);
          accu[mi][nh*2+nj] = __builtin_amdgcn_mfma_f32_16x16x32_bf16(a[mi], bu[nj], accu[mi][nh*2+nj], 0, 0, 0);
        }
    }
  };
  gload(0); sstore(0); __syncthreads();
  const int NT = H_DIM / 32;
  for (int kt = 0; kt < NT; ++kt){
    const int b = kt & 1;
    if (kt + 1 < NT) gload(kt + 1);
    compute(b);
    if (kt + 1 < NT) sstore(b ^ 1);
    __syncthreads();
  }
  const int bm = wr * 64 + ((lane >> 4) << 2);
  const int bn = wc * 64 + (lane & 15);
  #pragma unroll
  for (int mi = 0; mi < 4; ++mi)
    #pragma unroll
    for (int ni = 0; ni < 4; ++ni)
      #pragma unroll
      for (int r = 0; r < 4; ++r){
        float gv = accg[mi][ni][r];
        float uv = accu[mi][ni][r];
        float s  = gv / (1.0f + __expf(-gv));
        h[(size_t)(m0 + bm + mi*16 + r) * I_DIM + n0 + bn + ni*16] = f2bf(s * uv);
      }
}

__global__ __launch_bounds__(256, 2)
void k_down_fb(const u16* __restrict__ h, const float* __restrict__ wd,
               float* __restrict__ out)
{
  __shared__ unsigned char smem[40960];
  const int tid  = threadIdx.x;
  const int lane = tid & 63;
  const int wid  = tid >> 6;
  const int wr   = wid >> 1, wc = wid & 1;
  const int m0   = blockIdx.x * 128;
  const int n0   = blockIdx.y * 128;
  const int s_am = tid >> 1;
  const int s_ak = (tid & 1) * 16;
  const int s_bn = (tid & 63) * 2;
  const int s_bk = (tid >> 6) * 8;

  f32x4 acc[4][4];
  #pragma unroll
  for (int i = 0; i < 4; ++i)
    #pragma unroll
    for (int j = 0; j < 4; ++j) acc[i][j] = (f32x4)0.0f;

  u32x4 pha[2];
  f32x2 pb[8];
  auto gload = [&](int kt){
    const int k0 = kt * 32;
    const u16* ap = h + (size_t)(m0 + s_am) * I_DIM + k0 + s_ak;
    pha[0] = *(const u32x4*)(ap);
    pha[1] = *(const u32x4*)(ap + 8);
    #pragma unroll
    for (int r = 0; r < 8; ++r)
      pb[r] = *(const f32x2*)(wd + (size_t)(k0 + s_bk + r) * H_DIM + n0 + s_bn);
  };
  auto sstore = [&](int b){
    unsigned char* Ab = smem + b * 10240;
    *(u32x4*)(Ab + s_am * 80 + s_ak * 2)      = pha[0];
    *(u32x4*)(Ab + s_am * 80 + s_ak * 2 + 16) = pha[1];
    unsigned char* Bb = smem + 20480 + b * 10240;
    #pragma unroll
    for (int c = 0; c < 2; ++c){
      u32x4 v = { pack2bf(pb[0][c], pb[1][c]), pack2bf(pb[2][c], pb[3][c]),
                  pack2bf(pb[4][c], pb[5][c]), pack2bf(pb[6][c], pb[7][c]) };
      *(u32x4*)(Bb + (s_bn + c) * 80 + s_bk * 2) = v;
    }
  };
  const int koff = (lane >> 4) * 16;
  const int ar   = wr * 64 + (lane & 15);
  const int br   = wc * 64 + (lane & 15);
  auto compute = [&](int b){
    const unsigned char* Ab = smem + b * 10240;
    const unsigned char* Bb = smem + 20480 + b * 10240;
    bf16x8 a[4];
    #pragma unroll
    for (int mi = 0; mi < 4; ++mi)
      a[mi] = lds_frag(Ab + (ar + mi*16) * 80 + koff);
    #pragma unroll
    for (int nh = 0; nh < 2; ++nh){
      bf16x8 bb[2];
      #pragma unroll
      for (int nj = 0; nj < 2; ++nj)
        bb[nj] = lds_frag(Bb + (br + (nh*2+nj)*16) * 80 + koff);
      #pragma unroll
      for (int mi = 0; mi < 4; ++mi)
        #pragma unroll
        for (int nj = 0; nj < 2; ++nj)
          acc[mi][nh*2+nj] = __builtin_amdgcn_mfma_f32_16x16x32_bf16(a[mi], bb[nj], acc[mi][nh*2+nj], 0, 0, 0);
    }
  };
  gload(0); sstore(0); __syncthreads();
  const int NT = I_DIM / 32;
  for (int kt = 0; kt < NT; ++kt){
    const int b = kt & 1;
    if (kt + 1 < NT) gload(kt + 1);
    compute(b);
    if (kt + 1 < NT) sstore(b ^ 1);
    __syncthreads();
  }
  const int bm = wr * 64 + ((lane >> 4) << 2);
  const int bn = wc * 64 + (lane & 15);
  #pragma unroll
  for (int mi = 0; mi < 4; ++mi)
    #pragma unroll
    for (int ni = 0; ni < 4; ++ni)
      #pragma unroll
      for (int r = 0; r < 4; ++r)
        out[(size_t)(m0 + bm + mi*16 + r) * H_DIM + n0 + bn + ni*16] = acc[mi][ni][r];
}

// ---------------------------------------------------------------------------
extern "C" void kernel_launch(void* const* d_in, const int* in_sizes, int n_in,
                              void* d_out, int out_size, void* d_ws, size_t ws_size,
                              hipStream_t stream)
{
  const float* x  = (const float*)d_in[0];
  const float* wg = (const float*)d_in[1];
  const float* wu = (const float*)d_in[2];
  const float* wd = (const float*)d_in[3];
  float* out = (float*)d_out;

  const size_t X_OFF   = 0;            // x bf16:   33,554,432
  const size_t WGU_OFF = 33554432;     // wguT:    234,881,024
  const size_t WD_OFF  = 268435456;    // wdT:     117,440,512
  const size_t H_OFF   = 385875968;    // h:       117,440,512
  const size_t NEED    = 503316480;

  if (ws_size >= NEED){
    u16* xb  = (u16*)((char*)d_ws + X_OFF);
    u16* wgu = (u16*)((char*)d_ws + WGU_OFF);   // [28672][4096]
    u16* wdt = (u16*)((char*)d_ws + WD_OFF);    // [4096][14336]
    u16* h   = (u16*)((char*)d_ws + H_OFF);     // [4096][14336]

    long nx = (long)T_DIM * H_DIM;
    k_cast<<<(unsigned)((nx/8 + 255)/256), 256, 0, stream>>>(x, xb, nx);
    dim3 tg(H_DIM/64, I_DIM/64);
    k_transpose<<<tg, 256, 0, stream>>>(wg, wgu, H_DIM, I_DIM, 0);
    k_transpose<<<tg, 256, 0, stream>>>(wu, wgu, H_DIM, I_DIM, 16);
    dim3 td(I_DIM/64, H_DIM/64);
    k_transpose<<<td, 256, 0, stream>>>(wd, wdt, I_DIM, H_DIM, -1);

    // fused gate+up: M=4096, N=28672, K=4096 -> 16 x 112 = 1792 blocks
    gemm11<1><<<dim3(16 * (N2/256)), dim3(512), 0, stream>>>(
        xb, wgu, h, H_DIM, I_DIM, T_DIM/256);
    // down: M=4096, N=4096, K=14336 -> 16 x 16 = 256 blocks
    gemm11<0><<<dim3(16 * (H_DIM/256)), dim3(512), 0, stream>>>(
        h, wdt, out, I_DIM, H_DIM, T_DIM/256);
  } else {
    u16* h = (u16*)d_ws;
    size_t maxrows = ws_size / ((size_t)I_DIM * 2);
    int chunk = (int)(maxrows > (size_t)T_DIM ? (size_t)T_DIM : maxrows);
    chunk &= ~127;
    if (chunk < 128) chunk = 128;
    for (int r0 = 0; r0 < T_DIM; r0 += chunk){
      int rows = (T_DIM - r0 < chunk) ? (T_DIM - r0) : chunk;
      dim3 g1(rows / 128, I_DIM / 128);
      dim3 g2(rows / 128, H_DIM / 128);
      k_gateup_fb<<<g1, dim3(256), 0, stream>>>(x + (size_t)r0 * H_DIM, wg, wu, h);
      k_down_fb  <<<g2, dim3(256), 0, stream>>>(h, wd, out + (size_t)r0 * H_DIM);
    }
  }
}